// Round 1
// baseline (1715.404 us; speedup 1.0000x reference)
//
#include <hip/hip_runtime.h>
#include <cfloat>

// Problem constants: B=32, C=64, H=W=32, V=4096, SN=6, RESI=0.5, BETA=0.25
#define N_ELEM 2097152   // 32*64*32*32

__device__ __forceinline__ float blockReduceSum(float v) {
    __shared__ float red[4];
    #pragma unroll
    for (int off = 32; off; off >>= 1) v += __shfl_down(v, off, 64);
    int wid = threadIdx.x >> 6, lane = threadIdx.x & 63;
    if (lane == 0) red[wid] = v;
    __syncthreads();
    float r = 0.f;
    if (threadIdx.x == 0) {
        int nw = ((int)blockDim.x + 63) >> 6;
        for (int w = 0; w < nw; ++w) r += red[w];
    }
    __syncthreads();
    return r;
}

// half of squared L2 norm of each codebook row
__global__ void k_esq(const float* __restrict__ e, float* __restrict__ hesq) {
    int v = blockIdx.x * 256 + threadIdx.x;
    if (v >= 4096) return;
    const float4* r = (const float4*)(e + (size_t)v * 64);
    float s = 0.f;
    #pragma unroll
    for (int i = 0; i < 16; ++i) {
        float4 a = r[i];
        s += a.x * a.x + a.y * a.y + a.z * a.z + a.w * a.w;
    }
    hesq[v] = 0.5f * s;
}

// modulated conv weights: wmod = w * (1 + fc_w[:,0]*SN + fc_b), cond indexed [o*64+i]
__global__ void k_wmod(const float* __restrict__ w, const float* __restrict__ fcw,
                       const float* __restrict__ fcb, float* __restrict__ wmod) {
    int i = blockIdx.x * 256 + threadIdx.x;
    if (i >= 4 * 64 * 64 * 9) return;
    int k = i / (64 * 64 * 9);
    int r = i % (64 * 64 * 9);
    int oi = r / 9;
    float cond = fcw[k * 4096 + oi] * 6.0f + fcb[k * 4096 + oi];
    wmod[i] = w[i] * (1.0f + cond);
}

// block-mean pooling, one BLOCK per output element (for large s: si<=2)
template<bool DIFF>
__global__ void k_pool_wide(const float* __restrict__ A, const float* __restrict__ Bt,
                            float* __restrict__ out, int pn, int s) {
    int o = blockIdx.x;                     // [0, 2048*pn*pn)
    int px = o % pn;
    int t1 = o / pn;
    int py = t1 % pn;
    int t2 = t1 / pn;
    int c = t2 % 64, b = t2 / 64;
    size_t base = (((size_t)(b * 64 + c)) * 32 + (size_t)py * s) * 32 + (size_t)px * s;
    float acc = 0.f;
    int tot = s * s;
    for (int i = threadIdx.x; i < tot; i += blockDim.x) {
        int dy = i / s, dx = i % s;
        float v = A[base + dy * 32 + dx];
        if (DIFF) v -= Bt[base + dy * 32 + dx];
        acc += v;
    }
    acc = blockReduceSum(acc);
    if (threadIdx.x == 0) out[o] = acc / (float)tot;
}

// block-mean pooling, one THREAD per output element (s<=4: si>=3)
template<bool DIFF>
__global__ void k_pool_small(const float* __restrict__ A, const float* __restrict__ Bt,
                             float* __restrict__ out, int pn, int s) {
    int o = blockIdx.x * 256 + threadIdx.x;
    int total = 2048 * pn * pn;
    if (o >= total) return;
    int px = o % pn;
    int t1 = o / pn;
    int py = t1 % pn;
    int t2 = t1 / pn;
    int c = t2 % 64, b = t2 / 64;
    size_t base = (((size_t)(b * 64 + c)) * 32 + (size_t)py * s) * 32 + (size_t)px * s;
    float acc = 0.f;
    for (int dy = 0; dy < s; ++dy)
        for (int dx = 0; dx < s; ++dx) {
            float v = A[base + dy * 32 + dx];
            if (DIFF) v -= Bt[base + dy * 32 + dx];
            acc += v;
        }
    out[o] = acc / (float)(s * s);
}

// NCHW plane-major [64][pn2] per b -> [N][64] (pn2 >= 64, multiple of 64)
__global__ void k_trans_nc(const float* __restrict__ src, float* __restrict__ dst, int pn2) {
    __shared__ float t[64][65];
    int b = blockIdx.x;
    int p0 = blockIdx.y * 64;
    int lane = threadIdx.x & 63, r4 = threadIdx.x >> 6;
    #pragma unroll
    for (int i = 0; i < 16; ++i) {
        int c = i * 4 + r4;
        t[c][lane] = src[((size_t)b * 64 + c) * pn2 + p0 + lane];
    }
    __syncthreads();
    #pragma unroll
    for (int i = 0; i < 16; ++i) {
        int p = i * 4 + r4;
        dst[((size_t)(b * pn2 + p0 + p)) * 64 + lane] = t[lane][p];
    }
}

// small transpose for pn<=4 (N*64 <= 32768 elements)
__global__ void k_trans_small(const float* __restrict__ src, float* __restrict__ dst, int pn2) {
    int i = blockIdx.x * 256 + threadIdx.x;
    int total = 2048 * pn2;
    if (i >= total) return;
    int c = i & 63, n = i >> 6;
    int b = n / pn2, p = n % pn2;
    dst[i] = src[((size_t)b * 64 + c) * pn2 + p];
}

// [N][64] NHWC -> NCHW [b][c][1024]  (si=5 upsample is identity, just transpose back)
__global__ void k_trans_back(const float* __restrict__ hs, float* __restrict__ hup) {
    __shared__ float t[64][65];
    int b = blockIdx.x;
    int p0 = blockIdx.y * 64;
    int lane = threadIdx.x & 63, r4 = threadIdx.x >> 6;
    #pragma unroll
    for (int i = 0; i < 16; ++i) {
        int p = i * 4 + r4;
        t[p][lane] = hs[((size_t)(b * 1024 + p0 + p)) * 64 + lane];
    }
    __syncthreads();
    #pragma unroll
    for (int i = 0; i < 16; ++i) {
        int c = i * 4 + r4;
        hup[((size_t)(b * 64 + c)) * 1024 + p0 + lane] = t[lane][c];
    }
}

// VQ scan: per (point, code-slice) partial argmin of 0.5*|e|^2 - r.e
__global__ __launch_bounds__(256) void k_vq_scan(
        const float* __restrict__ nc, const float* __restrict__ embed,
        const float* __restrict__ hesq, float* __restrict__ scorep,
        int* __restrict__ idxp, int N, int CPS) {
    int n = blockIdx.x * 256 + threadIdx.x;
    int slice = blockIdx.y;
    float4 r[16];
    if (n < N) {
        const float4* p = (const float4*)(nc + (size_t)n * 64);
        #pragma unroll
        for (int i = 0; i < 16; ++i) r[i] = p[i];
    }
    float best = FLT_MAX;
    int bi = 0;
    int base = slice * CPS;
    for (int j = 0; j < CPS; ++j) {
        int code = __builtin_amdgcn_readfirstlane(base + j);   // force wave-uniform -> SGPR loads
        const float4* e4 = (const float4*)(embed + (size_t)code * 64);
        float d0 = 0.f, d1 = 0.f, d2 = 0.f, d3 = 0.f;
        #pragma unroll
        for (int i = 0; i < 16; i += 4) {
            float4 e0 = e4[i], e1 = e4[i + 1], e2 = e4[i + 2], e3 = e4[i + 3];
            d0 += e0.x * r[i].x     + e0.y * r[i].y     + e0.z * r[i].z     + e0.w * r[i].w;
            d1 += e1.x * r[i + 1].x + e1.y * r[i + 1].y + e1.z * r[i + 1].z + e1.w * r[i + 1].w;
            d2 += e2.x * r[i + 2].x + e2.y * r[i + 2].y + e2.z * r[i + 2].z + e2.w * r[i + 2].w;
            d3 += e3.x * r[i + 3].x + e3.y * r[i + 3].y + e3.z * r[i + 3].z + e3.w * r[i + 3].w;
        }
        float sc = hesq[code] - ((d0 + d1) + (d2 + d3));
        if (sc < best) { best = sc; bi = code; }   // strict <: first (lowest) index wins ties
    }
    if (n < N) {
        scorep[slice * N + n] = best;
        idxp[slice * N + n] = bi;
    }
}

__global__ void k_argmin(const float* __restrict__ scorep, const int* __restrict__ idxp,
                         int* __restrict__ idx, int N, int S) {
    int n = blockIdx.x * 256 + threadIdx.x;
    if (n >= N) return;
    float best = FLT_MAX;
    int bi = 0;
    for (int s = 0; s < S; ++s) {        // ascending slices -> lowest code index on ties
        float sc = scorep[s * N + n];
        if (sc < best) { best = sc; bi = idxp[s * N + n]; }
    }
    idx[n] = bi;
}

// gather codebook rows -> h_small [N][64] (wave reads one 256B row: coalesced)
__global__ void k_gather(const int* __restrict__ idx, const float* __restrict__ embed,
                         float* __restrict__ hs, int N) {
    int i = blockIdx.x * 256 + threadIdx.x;
    if (i >= N * 64) return;
    int n = i >> 6, c = i & 63;
    hs[i] = embed[(size_t)idx[n] * 64 + c];
}

// bilinear upsample pn->32 (half-pixel centers, edge clamp), NHWC small -> NCHW full
__global__ void k_upsample(const float* __restrict__ hs, float* __restrict__ hup, int pn) {
    int i = blockIdx.x * 256 + threadIdx.x;
    if (i >= N_ELEM) return;
    int x = i & 31, y = (i >> 5) & 31, c = (i >> 10) & 63, b = i >> 16;
    float scale = (float)pn * (1.0f / 32.0f);
    float sy = (y + 0.5f) * scale - 0.5f;
    float sx = (x + 0.5f) * scale - 0.5f;
    float fy0 = floorf(sy), fx0 = floorf(sx);
    float wy = sy - fy0, wx = sx - fx0;
    int y0 = max(0, min(pn - 1, (int)fy0));
    int y1 = max(0, min(pn - 1, (int)fy0 + 1));
    int x0 = max(0, min(pn - 1, (int)fx0));
    int x1 = max(0, min(pn - 1, (int)fx0 + 1));
    const float* hb = hs + (size_t)b * pn * pn * 64 + c;
    float v00 = hb[(size_t)(y0 * pn + x0) * 64];
    float v01 = hb[(size_t)(y0 * pn + x1) * 64];
    float v10 = hb[(size_t)(y1 * pn + x0) * 64];
    float v11 = hb[(size_t)(y1 * pn + x1) * 64];
    float v = (1.f - wy) * ((1.f - wx) * v00 + wx * v01) + wy * ((1.f - wx) * v10 + wx * v11);
    hup[i] = v;
}

// 3x3 SAME conv (modulated weights) + bias, blend 0.5h+0.5y, update f_hat/f_rest,
// and per-block partial of vq loss sum((f_hat_new - f)^2)
__global__ __launch_bounds__(256) void k_conv(
        const float* __restrict__ hup, const float* __restrict__ wmod,
        const float* __restrict__ bias, const float* __restrict__ f_in,
        float* __restrict__ f_hat, float* __restrict__ f_rest,
        float* __restrict__ vq_part) {
    __shared__ float tile[8 * 34 * 36];
    int b = blockIdx.x, og = blockIdx.y;
    int co0 = og * 4;
    int tid = threadIdx.x;
    int x = tid & 31, ybase = tid >> 5;
    float acc[4][4];
    #pragma unroll
    for (int j = 0; j < 4; ++j)
        #pragma unroll
        for (int co = 0; co < 4; ++co) acc[j][co] = 0.f;

    for (int ci0 = 0; ci0 < 64; ci0 += 8) {
        __syncthreads();
        for (int i = tid; i < 8 * 34 * 36; i += 256) {
            int ch = i / (34 * 36);
            int rem = i % (34 * 36);
            int yy = rem / 36, xx = rem % 36;
            int iy = yy - 1, ix = xx - 1;
            float v = 0.f;
            if (iy >= 0 && iy < 32 && ix >= 0 && ix < 32)
                v = hup[(((size_t)b * 64 + ci0 + ch) * 32 + iy) * 32 + ix];
            tile[i] = v;
        }
        __syncthreads();
        for (int ci = 0; ci < 8; ++ci) {
            float wv[4][9];
            #pragma unroll
            for (int co = 0; co < 4; ++co)
                #pragma unroll
                for (int t = 0; t < 9; ++t)
                    wv[co][t] = wmod[((size_t)(co0 + co) * 64 + ci0 + ci) * 9 + t];
            #pragma unroll
            for (int j = 0; j < 4; ++j) {
                int y = ybase + j * 8;
                const float* tb = tile + ci * (34 * 36) + y * 36 + x;
                float t00 = tb[0],  t01 = tb[1],  t02 = tb[2];
                float t10 = tb[36], t11 = tb[37], t12 = tb[38];
                float t20 = tb[72], t21 = tb[73], t22 = tb[74];
                #pragma unroll
                for (int co = 0; co < 4; ++co) {
                    acc[j][co] += wv[co][0] * t00 + wv[co][1] * t01 + wv[co][2] * t02
                                + wv[co][3] * t10 + wv[co][4] * t11 + wv[co][5] * t12
                                + wv[co][6] * t20 + wv[co][7] * t21 + wv[co][8] * t22;
                }
            }
        }
    }
    float local = 0.f;
    #pragma unroll
    for (int j = 0; j < 4; ++j) {
        int y = ybase + j * 8;
        #pragma unroll
        for (int co = 0; co < 4; ++co) {
            size_t o = (((size_t)b * 64 + co0 + co) * 32 + y) * 32 + x;
            float hconv = acc[j][co] + bias[co0 + co];
            float hv = hup[o];
            float hout = 0.5f * hv + 0.5f * hconv;   // h*(1-RESI) + y*RESI, RESI=0.5
            float fh = f_hat[o] + hout;
            f_hat[o] = fh;
            f_rest[o] -= hout;
            float d = fh - f_in[o];
            local += d * d;
        }
    }
    local = blockReduceSum(local);
    if (tid == 0) vq_part[b * 16 + og] = local;
}

// sum of squares of M elements -> per-block partials (fixed 512 blocks, grid-stride)
__global__ void k_sqsum(const float* __restrict__ v, float* __restrict__ part, int M) {
    float local = 0.f;
    for (int i = blockIdx.x * 256 + threadIdx.x; i < M; i += gridDim.x * 256) {
        float a = v[i];
        local += a * a;
    }
    local = blockReduceSum(local);
    if (threadIdx.x == 0) part[blockIdx.x] = local;
}

// final: reduce vq partials (6x512) and commit partials (6x512) -> out tail
__global__ void k_final(const float* __restrict__ vqp, const float* __restrict__ cmp,
                        float* __restrict__ out) {
    const int pn2s[6] = {1, 4, 16, 64, 256, 1024};
    float commit = 0.f;
    for (int si = 0; si < 6; ++si) {
        float l = 0.f;
        for (int i = threadIdx.x; i < 512; i += 256) l += vqp[si * 512 + i];
        l = blockReduceSum(l);
        if (threadIdx.x == 0) out[N_ELEM + si] = l / (float)N_ELEM;

        float csum = 0.f;
        for (int i = threadIdx.x; i < 512; i += 256) csum += cmp[si * 512 + i];
        csum = blockReduceSum(csum);
        if (threadIdx.x == 0) commit += csum / (float)(2048 * pn2s[si]) * 0.25f;
    }
    if (threadIdx.x == 0) out[N_ELEM + 6] = commit / 6.0f;
}

extern "C" void kernel_launch(void* const* d_in, const int* in_sizes, int n_in,
                              void* d_out, int out_size, void* d_ws, size_t ws_size,
                              hipStream_t stream) {
    const float* f     = (const float*)d_in[0];
    const float* embed = (const float*)d_in[1];
    const float* convw = (const float*)d_in[2];
    const float* convb = (const float*)d_in[3];
    const float* fcw   = (const float*)d_in[4];
    const float* fcb   = (const float*)d_in[5];
    float* out = (float*)d_out;
    float* ws  = (float*)d_ws;

    float* f_rest = ws;                       // 2097152
    float* pooled = ws + 2097152;             // 2097152
    float* restnc = ws + 4194304;             // 2097152 (aliased as h_small after scan)
    float* hs     = restnc;
    float* hup    = ws + 6291456;             // 2097152
    float* wmod   = ws + 8388608;             // 147456
    float* hesq   = ws + 8536064;             // 4096
    float* scorep = ws + 8540160;             // 262144
    int*   idxp   = (int*)(ws + 8802304);     // 262144
    int*   idx    = (int*)(ws + 9064448);     // 32768
    float* vqp    = ws + 9097216;             // 3072
    float* cmp    = ws + 9100288;             // 3072

    hipMemsetAsync(d_out, 0, (size_t)out_size * sizeof(float), stream);
    hipMemcpyAsync(f_rest, f, (size_t)N_ELEM * sizeof(float), hipMemcpyDeviceToDevice, stream);
    k_wmod<<<(147456 + 255) / 256, 256, 0, stream>>>(convw, fcw, fcb, wmod);
    k_esq<<<16, 256, 0, stream>>>(embed, hesq);

    const int pns[6]  = {1, 2, 4, 8, 16, 32};
    const int Ss[6]   = {64, 64, 64, 32, 16, 8};
    const int kidx[6] = {0, 0, 1, 2, 3, 3};

    for (int si = 0; si < 6; ++si) {
        int pn = pns[si], s = 32 / pn, pn2 = pn * pn;
        int N = 32 * pn2, S = Ss[si], CPS = 4096 / S;

        // 1. downsample f_rest -> rest_nc [N][64]
        if (si <= 2) {
            k_pool_wide<false><<<2048 * pn2, (s >= 16 ? 256 : 64), 0, stream>>>(f_rest, nullptr, pooled, pn, s);
            k_trans_small<<<(N * 64 + 255) / 256, 256, 0, stream>>>(pooled, restnc, pn2);
        } else if (si <= 4) {
            k_pool_small<false><<<(2048 * pn2 + 255) / 256, 256, 0, stream>>>(f_rest, nullptr, pooled, pn, s);
            k_trans_nc<<<dim3(32, pn2 / 64), 256, 0, stream>>>(pooled, restnc, pn2);
        } else {
            k_trans_nc<<<dim3(32, 16), 256, 0, stream>>>(f_rest, restnc, 1024);
        }

        // 2. nearest codebook entry
        k_vq_scan<<<dim3((N + 255) / 256, S), 256, 0, stream>>>(restnc, embed, hesq, scorep, idxp, N, CPS);
        k_argmin<<<(N + 255) / 256, 256, 0, stream>>>(scorep, idxp, idx, N, S);

        // 3. gather + upsample to full res NCHW
        k_gather<<<(N * 64 + 255) / 256, 256, 0, stream>>>(idx, embed, hs, N);
        if (si < 5) k_upsample<<<(N_ELEM + 255) / 256, 256, 0, stream>>>(hs, hup, pn);
        else        k_trans_back<<<dim3(32, 16), 256, 0, stream>>>(hs, hup);

        // 4. Phi conv + blend + state update + vq loss partials
        k_conv<<<dim3(32, 16), 256, 0, stream>>>(hup, wmod + kidx[si] * 36864, convb + kidx[si] * 64,
                                                 f, out, f_rest, vqp + si * 512);

        // 5. commit term: mean over patches of (mean(f_hat) - mean(f))^2
        if (si <= 2) k_pool_wide<true><<<2048 * pn2, (s >= 16 ? 256 : 64), 0, stream>>>(out, f, pooled, pn, s);
        else         k_pool_small<true><<<(2048 * pn2 + 255) / 256, 256, 0, stream>>>(out, f, pooled, pn, s);
        k_sqsum<<<512, 256, 0, stream>>>(pooled, cmp + si * 512, 2048 * pn2);
    }

    k_final<<<1, 256, 0, stream>>>(vqp, cmp, out);
}

// Round 3
// 1086.200 us; speedup vs baseline: 1.5793x; 1.5793x over previous
//
#include <hip/hip_runtime.h>
#include <cfloat>

// Problem constants: B=32, C=64, H=W=32, V=4096, SN=6, RESI=0.5, BETA=0.25
#define N_ELEM 2097152   // 32*64*32*32
#define TAU 2.0e-2f      // approx-score decision margin (>> worst-case split-bf16 error ~5e-4)

typedef short s16x8 __attribute__((ext_vector_type(8)));
typedef float f32x4 __attribute__((ext_vector_type(4)));

__device__ __forceinline__ unsigned short f2bf(float v) {   // RNE float->bf16 bits
    unsigned u = __float_as_uint(v);
    u += 0x7FFFu + ((u >> 16) & 1u);
    return (unsigned short)(u >> 16);
}
__device__ __forceinline__ float bf2f(unsigned short h) {
    return __uint_as_float(((unsigned)h) << 16);
}

__device__ __forceinline__ float blockReduceSum(float v) {
    __shared__ float red[4];
    #pragma unroll
    for (int off = 32; off; off >>= 1) v += __shfl_down(v, off, 64);
    int wid = threadIdx.x >> 6, lane = threadIdx.x & 63;
    if (lane == 0) red[wid] = v;
    __syncthreads();
    float r = 0.f;
    if (threadIdx.x == 0) {
        int nw = ((int)blockDim.x + 63) >> 6;
        for (int w = 0; w < nw; ++w) r += red[w];
    }
    __syncthreads();
    return r;
}

// codebook prep: half squared norms (f32) + bf16 hi/lo planes
__global__ void k_embprep(const float* __restrict__ e, float* __restrict__ hesq,
                          unsigned short* __restrict__ ehi, unsigned short* __restrict__ elo) {
    int v = blockIdx.x * 256 + threadIdx.x;
    if (v >= 4096) return;
    const float4* r = (const float4*)(e + (size_t)v * 64);
    float s = 0.f;
    #pragma unroll
    for (int i = 0; i < 16; ++i) {
        float4 a = r[i];
        s += a.x * a.x + a.y * a.y + a.z * a.z + a.w * a.w;
    }
    hesq[v] = 0.5f * s;
    for (int i = 0; i < 64; ++i) {
        float x = e[(size_t)v * 64 + i];
        unsigned short h = f2bf(x);
        ehi[(size_t)v * 64 + i] = h;
        elo[(size_t)v * 64 + i] = f2bf(x - bf2f(h));
    }
}

// modulated conv weights
__global__ void k_wmod(const float* __restrict__ w, const float* __restrict__ fcw,
                       const float* __restrict__ fcb, float* __restrict__ wmod) {
    int i = blockIdx.x * 256 + threadIdx.x;
    if (i >= 4 * 64 * 64 * 9) return;
    int k = i / (64 * 64 * 9);
    int r = i % (64 * 64 * 9);
    int oi = r / 9;
    float cond = fcw[k * 4096 + oi] * 6.0f + fcb[k * 4096 + oi];
    wmod[i] = w[i] * (1.0f + cond);
}

// block-mean pooling, one BLOCK per output element (large s: si<=2)
template<bool DIFF>
__global__ void k_pool_wide(const float* __restrict__ A, const float* __restrict__ Bt,
                            float* __restrict__ out, int pn, int s) {
    int o = blockIdx.x;
    int px = o % pn;
    int t1 = o / pn;
    int py = t1 % pn;
    int t2 = t1 / pn;
    int c = t2 % 64, b = t2 / 64;
    size_t base = (((size_t)(b * 64 + c)) * 32 + (size_t)py * s) * 32 + (size_t)px * s;
    float acc = 0.f;
    int tot = s * s;
    for (int i = threadIdx.x; i < tot; i += blockDim.x) {
        int dy = i / s, dx = i % s;
        float v = A[base + dy * 32 + dx];
        if (DIFF) v -= Bt[base + dy * 32 + dx];
        acc += v;
    }
    acc = blockReduceSum(acc);
    if (threadIdx.x == 0) out[o] = acc / (float)tot;
}

// block-mean pooling, one THREAD per output element (s<=4: si>=3)
template<bool DIFF>
__global__ void k_pool_small(const float* __restrict__ A, const float* __restrict__ Bt,
                             float* __restrict__ out, int pn, int s) {
    int o = blockIdx.x * 256 + threadIdx.x;
    int total = 2048 * pn * pn;
    if (o >= total) return;
    int px = o % pn;
    int t1 = o / pn;
    int py = t1 % pn;
    int t2 = t1 / pn;
    int c = t2 % 64, b = t2 / 64;
    size_t base = (((size_t)(b * 64 + c)) * 32 + (size_t)py * s) * 32 + (size_t)px * s;
    float acc = 0.f;
    for (int dy = 0; dy < s; ++dy)
        for (int dx = 0; dx < s; ++dx) {
            float v = A[base + dy * 32 + dx];
            if (DIFF) v -= Bt[base + dy * 32 + dx];
            acc += v;
        }
    out[o] = acc / (float)(s * s);
}

// NCHW plane-major [64][pn2] per b -> [N][64] f32 + bf16 hi/lo (pn2 multiple of 64)
__global__ void k_trans_nc(const float* __restrict__ src, float* __restrict__ dst,
                           unsigned short* __restrict__ dhi, unsigned short* __restrict__ dlo,
                           int pn2) {
    __shared__ float t[64][65];
    int b = blockIdx.x;
    int p0 = blockIdx.y * 64;
    int lane = threadIdx.x & 63, r4 = threadIdx.x >> 6;
    #pragma unroll
    for (int i = 0; i < 16; ++i) {
        int c = i * 4 + r4;
        t[c][lane] = src[((size_t)b * 64 + c) * pn2 + p0 + lane];
    }
    __syncthreads();
    #pragma unroll
    for (int i = 0; i < 16; ++i) {
        int p = i * 4 + r4;
        size_t o = ((size_t)(b * pn2 + p0 + p)) * 64 + lane;
        float v = t[lane][p];
        unsigned short h = f2bf(v);
        dst[o] = v;
        dhi[o] = h;
        dlo[o] = f2bf(v - bf2f(h));
    }
}

// small transpose for pn<=4
__global__ void k_trans_small(const float* __restrict__ src, float* __restrict__ dst,
                              unsigned short* __restrict__ dhi, unsigned short* __restrict__ dlo,
                              int pn2) {
    int i = blockIdx.x * 256 + threadIdx.x;
    int total = 2048 * pn2;
    if (i >= total) return;
    int c = i & 63, n = i >> 6;
    int b = n / pn2, p = n % pn2;
    float v = src[((size_t)b * 64 + c) * pn2 + p];
    unsigned short h = f2bf(v);
    dst[i] = v;
    dhi[i] = h;
    dlo[i] = f2bf(v - bf2f(h));
}

// [N][64] NHWC -> NCHW (si=5: upsample is identity)
__global__ void k_trans_back(const float* __restrict__ hs, float* __restrict__ hup) {
    __shared__ float t[64][65];
    int b = blockIdx.x;
    int p0 = blockIdx.y * 64;
    int lane = threadIdx.x & 63, r4 = threadIdx.x >> 6;
    #pragma unroll
    for (int i = 0; i < 16; ++i) {
        int p = i * 4 + r4;
        t[p][lane] = hs[((size_t)(b * 1024 + p0 + p)) * 64 + lane];
    }
    __syncthreads();
    #pragma unroll
    for (int i = 0; i < 16; ++i) {
        int c = i * 4 + r4;
        hup[((size_t)(b * 64 + c)) * 1024 + p0 + lane] = t[lane][c];
    }
}

// ---- MFMA VQ scan: approx scores via split-bf16 (3 terms), per-point top-2 ----
// D[code][point]: A = codes (LDS, xor-swizzled), B = points (regs).
// A/B use the same slot->channel rule => contraction is k-permutation invariant.
__global__ __launch_bounds__(256) void k_vq_mfma(
        const unsigned short* __restrict__ resthi, const unsigned short* __restrict__ restlo,
        const unsigned short* __restrict__ embhi,  const unsigned short* __restrict__ emblo,
        const float* __restrict__ hesq,
        float* __restrict__ m1v_, int* __restrict__ m1i_,
        float* __restrict__ m2v_, int* __restrict__ m2i_,
        int N, int CPS) {
    __shared__ __align__(16) unsigned short lah[64 * 64];
    __shared__ __align__(16) unsigned short lal[64 * 64];
    __shared__ __align__(16) float lq[64];
    int tid = threadIdx.x;
    int lane = tid & 63, wv = tid >> 6;
    int split = blockIdx.y;
    int p0 = blockIdx.x * 64 + wv * 16;
    int pt = p0 + (lane & 15);
    int ptc = min(pt, N - 1);
    int ko8 = (lane >> 4) * 8;     // channel octet per lane group

    const unsigned short* rb = resthi + (size_t)ptc * 64;
    const unsigned short* rl = restlo + (size_t)ptc * 64;
    s16x8 bh0 = *(const s16x8*)(rb + ko8);
    s16x8 bh1 = *(const s16x8*)(rb + 32 + ko8);
    s16x8 bl0 = *(const s16x8*)(rl + ko8);
    s16x8 bl1 = *(const s16x8*)(rl + 32 + ko8);

    float m1v = FLT_MAX, m2v = FLT_MAX;
    int m1i = 0, m2i = 0;

    int cbeg = split * CPS;
    for (int oc = 0; oc < CPS; oc += 64) {
        int cb = cbeg + oc;
        __syncthreads();
        // stage 64 codes (hi+lo, 16KB total) + hesq chunk, xor-swizzled rows.
        // 64 rows x 8 chunks of 16B per plane = 512 chunks; 256 threads -> 2 each.
        for (int t = tid; t < 512; t += 256) {
            int cc = t >> 3, part = t & 7;
            int bo = (cc * 128 + part * 16) ^ ((cc & 7) << 4);
            *(uint4*)((char*)lah + bo) = *(const uint4*)(embhi + (size_t)(cb + cc) * 64 + part * 8);
            *(uint4*)((char*)lal + bo) = *(const uint4*)(emblo + (size_t)(cb + cc) * 64 + part * 8);
        }
        if (tid < 64) lq[tid] = hesq[cb + tid];
        __syncthreads();
        #pragma unroll
        for (int sub = 0; sub < 4; ++sub) {
            int cl = sub * 16 + (lane & 15);
            int sw = (cl & 7) << 4;
            int rowb = cl * 128;
            s16x8 ah0 = *(const s16x8*)((const char*)lah + ((rowb + ko8 * 2) ^ sw));
            s16x8 ah1 = *(const s16x8*)((const char*)lah + ((rowb + 64 + ko8 * 2) ^ sw));
            s16x8 al0 = *(const s16x8*)((const char*)lal + ((rowb + ko8 * 2) ^ sw));
            s16x8 al1 = *(const s16x8*)((const char*)lal + ((rowb + 64 + ko8 * 2) ^ sw));
            f32x4 acc = {0.f, 0.f, 0.f, 0.f};
            acc = __builtin_amdgcn_mfma_f32_16x16x32_bf16(ah0, bh0, acc, 0, 0, 0);
            acc = __builtin_amdgcn_mfma_f32_16x16x32_bf16(ah1, bh1, acc, 0, 0, 0);
            acc = __builtin_amdgcn_mfma_f32_16x16x32_bf16(ah0, bl0, acc, 0, 0, 0);
            acc = __builtin_amdgcn_mfma_f32_16x16x32_bf16(ah1, bl1, acc, 0, 0, 0);
            acc = __builtin_amdgcn_mfma_f32_16x16x32_bf16(al0, bh0, acc, 0, 0, 0);
            acc = __builtin_amdgcn_mfma_f32_16x16x32_bf16(al1, bh1, acc, 0, 0, 0);
            int crow = cb + sub * 16 + (lane >> 4) * 4;
            f32x4 q = *(const f32x4*)(lq + sub * 16 + (lane >> 4) * 4);
            #pragma unroll
            for (int r = 0; r < 4; ++r) {
                float s = q[r] - acc[r];
                int c = crow + r;
                bool lt1 = s < m1v, lt2 = s < m2v;
                float nm2v = lt2 ? s : m2v; int nm2i = lt2 ? c : m2i;
                nm2v = lt1 ? m1v : nm2v;    nm2i = lt1 ? m1i : nm2i;
                m1v = lt1 ? s : m1v;        m1i = lt1 ? c : m1i;
                m2v = nm2v; m2i = nm2i;
            }
        }
    }
    // merge across the 4 lane groups holding the same point column
    #pragma unroll
    for (int off = 16; off <= 32; off <<= 1) {
        float o1v = __shfl_xor(m1v, off, 64); int o1i = __shfl_xor(m1i, off, 64);
        float o2v = __shfl_xor(m2v, off, 64); int o2i = __shfl_xor(m2i, off, 64);
        if (o1v < m1v) {
            float c2v = (m1v < o2v) ? m1v : o2v; int c2i = (m1v < o2v) ? m1i : o2i;
            m1v = o1v; m1i = o1i; m2v = c2v; m2i = c2i;
        } else if (o1v < m2v) {
            m2v = o1v; m2i = o1i;
        }
    }
    if ((lane >> 4) == 0 && pt < N) {
        size_t o = (size_t)split * N + pt;
        m1v_[o] = m1v; m1i_[o] = m1i; m2v_[o] = m2v; m2i_[o] = m2i;
    }
}

// merge split partials; decide or flag for exact fallback
__global__ void k_vq_combine(const float* __restrict__ m1v_, const int* __restrict__ m1i_,
                             const float* __restrict__ m2v_, const int* __restrict__ m2i_,
                             int* __restrict__ idx, int* __restrict__ flag, int* __restrict__ count,
                             int N, int SPLITS) {
    int n = blockIdx.x * 256 + threadIdx.x;
    if (n >= N) return;
    float a1v = m1v_[n], a2v = m2v_[n];
    int a1i = m1i_[n], a2i = m2i_[n];
    for (int s = 1; s < SPLITS; ++s) {
        size_t o = (size_t)s * N + n;
        float b1v = m1v_[o], b2v = m2v_[o];
        int b1i = m1i_[o], b2i = m2i_[o];
        if (b1v < a1v) {
            float c2v = (a1v < b2v) ? a1v : b2v; int c2i = (a1v < b2v) ? a1i : b2i;
            a1v = b1v; a1i = b1i; a2v = c2v; a2i = c2i;
        } else if (b1v < a2v) {
            a2v = b1v; a2i = b1i;
        }
    }
    idx[n] = a1i;
    if (a2v - a1v < TAU) {
        int p = atomicAdd(count, 1);
        flag[p] = n;
    }
}

// exact f32 rescan for flagged points (batches of 32 points x 256-code splits)
__global__ __launch_bounds__(256) void k_vq_exact(
        const float* __restrict__ restnc, const float* __restrict__ embed,
        const float* __restrict__ hesq, const int* __restrict__ flag,
        const int* __restrict__ count, unsigned long long* __restrict__ pmin) {
    __shared__ float rs[32 * 64];
    __shared__ unsigned long long red[4];
    int tid = threadIdx.x;
    int lane = tid & 63, wv = tid >> 6;
    int cnt = *count;
    int nb = (cnt + 31) >> 5;
    int ntask = nb * 16;
    for (int task = blockIdx.x; task < ntask; task += gridDim.x) {
        int batch = task >> 4, spl = task & 15;
        int lbase = batch << 5;
        int npts = min(32, cnt - lbase);
        __syncthreads();
        for (int i = tid; i < npts * 64; i += 256) {
            int li = i >> 6;
            rs[i] = restnc[(size_t)flag[lbase + li] * 64 + (i & 63)];
        }
        __syncthreads();
        int code = spl * 256 + tid;
        const float4* e4 = (const float4*)(embed + (size_t)code * 64);
        float4 e[16];
        #pragma unroll
        for (int i = 0; i < 16; ++i) e[i] = e4[i];
        float hq = hesq[code];
        for (int p = 0; p < npts; ++p) {
            const float4* r4 = (const float4*)(rs + p * 64);
            float d0 = 0.f, d1 = 0.f, d2 = 0.f, d3 = 0.f;
            #pragma unroll
            for (int i = 0; i < 16; i += 4) {
                float4 e0 = e[i], e1 = e[i + 1], e2 = e[i + 2], e3 = e[i + 3];
                d0 += e0.x * r4[i].x     + e0.y * r4[i].y     + e0.z * r4[i].z     + e0.w * r4[i].w;
                d1 += e1.x * r4[i + 1].x + e1.y * r4[i + 1].y + e1.z * r4[i + 1].z + e1.w * r4[i + 1].w;
                d2 += e2.x * r4[i + 2].x + e2.y * r4[i + 2].y + e2.z * r4[i + 2].z + e2.w * r4[i + 2].w;
                d3 += e3.x * r4[i + 3].x + e3.y * r4[i + 3].y + e3.z * r4[i + 3].z + e3.w * r4[i + 3].w;
            }
            float s = hq - ((d0 + d1) + (d2 + d3));
            unsigned u = __float_as_uint(s);
            u = (u & 0x80000000u) ? ~u : (u | 0x80000000u);
            unsigned long long pk = (((unsigned long long)u) << 32) | (unsigned)code;
            #pragma unroll
            for (int off = 32; off; off >>= 1) {
                unsigned long long o = __shfl_down(pk, off, 64);
                if (o < pk) pk = o;
            }
            if (lane == 0) red[wv] = pk;
            __syncthreads();
            if (tid == 0) {
                unsigned long long m = red[0];
                for (int w = 1; w < 4; ++w) if (red[w] < m) m = red[w];
                atomicMin(pmin + flag[lbase + p], m);
            }
            __syncthreads();
        }
    }
}

// gather codebook rows (pmin overrides idx for flagged points)
__global__ void k_gather(const int* __restrict__ idx, const unsigned long long* __restrict__ pmin,
                         const float* __restrict__ embed, float* __restrict__ hs, int N) {
    int i = blockIdx.x * 256 + threadIdx.x;
    if (i >= N * 64) return;
    int n = i >> 6, c = i & 63;
    unsigned long long pv = pmin[n];
    int id = (pv != 0xFFFFFFFFFFFFFFFFull) ? (int)(pv & 0xFFFFFFFFull) : idx[n];
    hs[i] = embed[(size_t)id * 64 + c];
}

// bilinear upsample pn->32 (half-pixel centers, edge clamp), NHWC small -> NCHW full
__global__ void k_upsample(const float* __restrict__ hs, float* __restrict__ hup, int pn) {
    int i = blockIdx.x * 256 + threadIdx.x;
    if (i >= N_ELEM) return;
    int x = i & 31, y = (i >> 5) & 31, c = (i >> 10) & 63, b = i >> 16;
    float scale = (float)pn * (1.0f / 32.0f);
    float sy = (y + 0.5f) * scale - 0.5f;
    float sx = (x + 0.5f) * scale - 0.5f;
    float fy0 = floorf(sy), fx0 = floorf(sx);
    float wy = sy - fy0, wx = sx - fx0;
    int y0 = max(0, min(pn - 1, (int)fy0));
    int y1 = max(0, min(pn - 1, (int)fy0 + 1));
    int x0 = max(0, min(pn - 1, (int)fx0));
    int x1 = max(0, min(pn - 1, (int)fx0 + 1));
    const float* hb = hs + (size_t)b * pn * pn * 64 + c;
    float v00 = hb[(size_t)(y0 * pn + x0) * 64];
    float v01 = hb[(size_t)(y0 * pn + x1) * 64];
    float v10 = hb[(size_t)(y1 * pn + x0) * 64];
    float v11 = hb[(size_t)(y1 * pn + x1) * 64];
    float v = (1.f - wy) * ((1.f - wx) * v00 + wx * v01) + wy * ((1.f - wx) * v10 + wx * v11);
    hup[i] = v;
}

// 3x3 SAME conv + bias, blend, update f_hat/f_rest, vq-loss partials.
// grid (32 b, 16 og, 2 y-half); LDS tile 8ci x 18 x 36 = 20.7KB -> 4 blocks/CU.
__global__ __launch_bounds__(256) void k_conv(
        const float* __restrict__ hup, const float* __restrict__ wmod,
        const float* __restrict__ bias, const float* __restrict__ f_in,
        float* __restrict__ f_hat, float* __restrict__ f_rest,
        float* __restrict__ vq_part) {
    __shared__ float tile[8 * 18 * 36];
    int b = blockIdx.x, og = blockIdx.y, zh = blockIdx.z;
    int co0 = og * 4;
    int y0 = zh * 16;
    int tid = threadIdx.x;
    int x = tid & 31, ybase = tid >> 5;
    float acc[2][4];
    #pragma unroll
    for (int j = 0; j < 2; ++j)
        #pragma unroll
        for (int co = 0; co < 4; ++co) acc[j][co] = 0.f;

    for (int ci0 = 0; ci0 < 64; ci0 += 8) {
        __syncthreads();
        for (int i = tid; i < 8 * 18 * 36; i += 256) {
            int ch = i / (18 * 36);
            int rem = i % (18 * 36);
            int yy = rem / 36, xx = rem % 36;
            int iy = y0 + yy - 1, ix = xx - 1;
            float v = 0.f;
            if (iy >= 0 && iy < 32 && ix >= 0 && ix < 32)
                v = hup[(((size_t)b * 64 + ci0 + ch) * 32 + iy) * 32 + ix];
            tile[i] = v;
        }
        __syncthreads();
        for (int ci = 0; ci < 8; ++ci) {
            float wv[4][9];
            #pragma unroll
            for (int co = 0; co < 4; ++co)
                #pragma unroll
                for (int t = 0; t < 9; ++t)
                    wv[co][t] = wmod[((size_t)(co0 + co) * 64 + ci0 + ci) * 9 + t];
            #pragma unroll
            for (int j = 0; j < 2; ++j) {
                int yy = ybase + j * 8;
                const float* tb = tile + ci * (18 * 36) + yy * 36 + x;
                float t00 = tb[0],  t01 = tb[1],  t02 = tb[2];
                float t10 = tb[36], t11 = tb[37], t12 = tb[38];
                float t20 = tb[72], t21 = tb[73], t22 = tb[74];
                #pragma unroll
                for (int co = 0; co < 4; ++co) {
                    acc[j][co] += wv[co][0] * t00 + wv[co][1] * t01 + wv[co][2] * t02
                                + wv[co][3] * t10 + wv[co][4] * t11 + wv[co][5] * t12
                                + wv[co][6] * t20 + wv[co][7] * t21 + wv[co][8] * t22;
                }
            }
        }
    }
    float local = 0.f;
    #pragma unroll
    for (int j = 0; j < 2; ++j) {
        int y = y0 + ybase + j * 8;
        #pragma unroll
        for (int co = 0; co < 4; ++co) {
            size_t o = (((size_t)b * 64 + co0 + co) * 32 + y) * 32 + x;
            float hconv = acc[j][co] + bias[co0 + co];
            float hv = hup[o];
            float hout = 0.5f * hv + 0.5f * hconv;
            float fh = f_hat[o] + hout;
            f_hat[o] = fh;
            f_rest[o] -= hout;
            float d = fh - f_in[o];
            local += d * d;
        }
    }
    local = blockReduceSum(local);
    if (tid == 0) vq_part[(b * 16 + og) * 2 + zh] = local;
}

// sum of squares -> per-block partials
__global__ void k_sqsum(const float* __restrict__ v, float* __restrict__ part, int M) {
    float local = 0.f;
    for (int i = blockIdx.x * 256 + threadIdx.x; i < M; i += gridDim.x * 256) {
        float a = v[i];
        local += a * a;
    }
    local = blockReduceSum(local);
    if (threadIdx.x == 0) part[blockIdx.x] = local;
}

// final: reduce vq partials (6x1024) and commit partials (6x512)
__global__ void k_final(const float* __restrict__ vqp, const float* __restrict__ cmp,
                        float* __restrict__ out) {
    const int pn2s[6] = {1, 4, 16, 64, 256, 1024};
    float commit = 0.f;
    for (int si = 0; si < 6; ++si) {
        float l = 0.f;
        for (int i = threadIdx.x; i < 1024; i += 256) l += vqp[si * 1024 + i];
        l = blockReduceSum(l);
        if (threadIdx.x == 0) out[N_ELEM + si] = l / (float)N_ELEM;

        float csum = 0.f;
        for (int i = threadIdx.x; i < 512; i += 256) csum += cmp[si * 512 + i];
        csum = blockReduceSum(csum);
        if (threadIdx.x == 0) commit += csum / (float)(2048 * pn2s[si]) * 0.25f;
    }
    if (threadIdx.x == 0) out[N_ELEM + 6] = commit / 6.0f;
}

extern "C" void kernel_launch(void* const* d_in, const int* in_sizes, int n_in,
                              void* d_out, int out_size, void* d_ws, size_t ws_size,
                              hipStream_t stream) {
    const float* f     = (const float*)d_in[0];
    const float* embed = (const float*)d_in[1];
    const float* convw = (const float*)d_in[2];
    const float* convb = (const float*)d_in[3];
    const float* fcw   = (const float*)d_in[4];
    const float* fcb   = (const float*)d_in[5];
    float* out = (float*)d_out;
    float* ws  = (float*)d_ws;

    float* f_rest = ws;                                   // 2097152
    float* poolhup = ws + 2097152;                        // 2097152 (pooled & hup alias)
    float* restnc = ws + 4194304;                         // 2097152 (hs alias after exact)
    float* hs     = restnc;
    float* wmod   = ws + 6291456;                         // 147456
    float* hesq   = ws + 6438912;                         // 4096
    unsigned short* resthi = (unsigned short*)(ws + 6443008);   // 2097152 u16
    unsigned short* restlo = (unsigned short*)(ws + 7491584);   // 2097152 u16
    unsigned short* embhi  = (unsigned short*)(ws + 8540160);   // 262144 u16
    unsigned short* emblo  = (unsigned short*)(ws + 8671232);   // 262144 u16
    float* m1v    = ws + 8802304;                         // 65536
    float* m2v    = ws + 8867840;                         // 65536
    int*   m1i    = (int*)(ws + 8933376);                 // 65536
    int*   m2i    = (int*)(ws + 8998912);                 // 65536
    int*   idx    = (int*)(ws + 9064448);                 // 32768
    int*   flag   = (int*)(ws + 9097216);                 // 32768
    int*   count  = (int*)(ws + 9129984);                 // 64 (pad)
    unsigned long long* pmin = (unsigned long long*)(ws + 9130048); // 32768 u64
    float* vqp    = ws + 9195584;                         // 6144 (6*1024)
    float* cmp    = ws + 9201728;                         // 3072 (6*512)

    hipMemsetAsync(d_out, 0, (size_t)out_size * sizeof(float), stream);
    hipMemcpyAsync(f_rest, f, (size_t)N_ELEM * sizeof(float), hipMemcpyDeviceToDevice, stream);
    k_wmod<<<(147456 + 255) / 256, 256, 0, stream>>>(convw, fcw, fcb, wmod);
    k_embprep<<<16, 256, 0, stream>>>(embed, hesq, embhi, emblo);

    const int pns[6]    = {1, 2, 4, 8, 16, 32};
    const int splits[6] = {64, 32, 16, 8, 4, 2};
    const int kidx[6]   = {0, 0, 1, 2, 3, 3};

    for (int si = 0; si < 6; ++si) {
        int pn = pns[si], s = 32 / pn, pn2 = pn * pn;
        int N = 32 * pn2, SPL = splits[si], CPS = 4096 / SPL;
        float* pooled = poolhup;
        float* hup = poolhup;

        // 1. downsample f_rest -> rest [N][64] f32 + bf16 hi/lo
        if (si <= 2) {
            k_pool_wide<false><<<2048 * pn2, (s >= 16 ? 256 : 64), 0, stream>>>(f_rest, nullptr, pooled, pn, s);
            k_trans_small<<<(N * 64 + 255) / 256, 256, 0, stream>>>(pooled, restnc, resthi, restlo, pn2);
        } else if (si <= 4) {
            k_pool_small<false><<<(2048 * pn2 + 255) / 256, 256, 0, stream>>>(f_rest, nullptr, pooled, pn, s);
            k_trans_nc<<<dim3(32, pn2 / 64), 256, 0, stream>>>(pooled, restnc, resthi, restlo, pn2);
        } else {
            k_trans_nc<<<dim3(32, 16), 256, 0, stream>>>(f_rest, restnc, resthi, restlo, 1024);
        }

        // 2. nearest codebook entry: MFMA approx top-2 -> combine -> exact fallback
        hipMemsetAsync(count, 0, sizeof(int), stream);
        hipMemsetAsync(pmin, 0xFF, (size_t)N * 8, stream);
        k_vq_mfma<<<dim3((N + 63) / 64, SPL), 256, 0, stream>>>(resthi, restlo, embhi, emblo, hesq,
                                                                m1v, m1i, m2v, m2i, N, CPS);
        k_vq_combine<<<(N + 255) / 256, 256, 0, stream>>>(m1v, m1i, m2v, m2i, idx, flag, count, N, SPL);
        k_vq_exact<<<1024, 256, 0, stream>>>(restnc, embed, hesq, flag, count, pmin);

        // 3. gather + upsample to full res NCHW
        k_gather<<<(N * 64 + 255) / 256, 256, 0, stream>>>(idx, pmin, embed, hs, N);
        if (si < 5) k_upsample<<<(N_ELEM + 255) / 256, 256, 0, stream>>>(hs, hup, pn);
        else        k_trans_back<<<dim3(32, 16), 256, 0, stream>>>(hs, hup);

        // 4. Phi conv + blend + state update + vq loss partials
        k_conv<<<dim3(32, 16, 2), 256, 0, stream>>>(hup, wmod + kidx[si] * 36864, convb + kidx[si] * 64,
                                                    f, out, f_rest, vqp + si * 1024);

        // 5. commit term
        if (si <= 2) k_pool_wide<true><<<2048 * pn2, (s >= 16 ? 256 : 64), 0, stream>>>(out, f, pooled, pn, s);
        else         k_pool_small<true><<<(2048 * pn2 + 255) / 256, 256, 0, stream>>>(out, f, pooled, pn, s);
        k_sqsum<<<512, 256, 0, stream>>>(pooled, cmp + si * 512, 2048 * pn2);
    }

    k_final<<<1, 256, 0, stream>>>(vqp, cmp, out);
}

// Round 4
// 715.945 us; speedup vs baseline: 2.3960x; 1.5172x over previous
//
#include <hip/hip_runtime.h>
#include <cfloat>

// Problem constants: B=32, C=64, H=W=32, V=4096, SN=6, RESI=0.5, BETA=0.25
#define N_ELEM 2097152   // 32*64*32*32
#define TAU 2.0e-2f      // approx-score decision margin (>> worst-case split-bf16 error ~5e-4)

typedef short s16x8 __attribute__((ext_vector_type(8)));
typedef float f32x4 __attribute__((ext_vector_type(4)));

__device__ __forceinline__ unsigned short f2bf(float v) {   // RNE float->bf16 bits
    unsigned u = __float_as_uint(v);
    u += 0x7FFFu + ((u >> 16) & 1u);
    return (unsigned short)(u >> 16);
}
__device__ __forceinline__ float bf2f(unsigned short h) {
    return __uint_as_float(((unsigned)h) << 16);
}

__device__ __forceinline__ float blockReduceSum(float v) {
    __shared__ float red[4];
    #pragma unroll
    for (int off = 32; off; off >>= 1) v += __shfl_down(v, off, 64);
    int wid = threadIdx.x >> 6, lane = threadIdx.x & 63;
    if (lane == 0) red[wid] = v;
    __syncthreads();
    float r = 0.f;
    if (threadIdx.x == 0) {
        int nw = ((int)blockDim.x + 63) >> 6;
        for (int w = 0; w < nw; ++w) r += red[w];
    }
    __syncthreads();
    return r;
}

// codebook prep: half squared norms (f32) + bf16 hi/lo planes
__global__ void k_embprep(const float* __restrict__ e, float* __restrict__ hesq,
                          unsigned short* __restrict__ ehi, unsigned short* __restrict__ elo) {
    int v = blockIdx.x * 256 + threadIdx.x;
    if (v >= 4096) return;
    const float4* r = (const float4*)(e + (size_t)v * 64);
    float s = 0.f;
    #pragma unroll
    for (int i = 0; i < 16; ++i) {
        float4 a = r[i];
        s += a.x * a.x + a.y * a.y + a.z * a.z + a.w * a.w;
    }
    hesq[v] = 0.5f * s;
    for (int i = 0; i < 64; ++i) {
        float x = e[(size_t)v * 64 + i];
        unsigned short h = f2bf(x);
        ehi[(size_t)v * 64 + i] = h;
        elo[(size_t)v * 64 + i] = f2bf(x - bf2f(h));
    }
}

// modulated conv weights -> MFMA layout [k][tap][co][ci] bf16 hi/lo
__global__ void k_wmod(const float* __restrict__ w, const float* __restrict__ fcw,
                       const float* __restrict__ fcb,
                       unsigned short* __restrict__ wh, unsigned short* __restrict__ wl) {
    int i = blockIdx.x * 256 + threadIdx.x;
    if (i >= 4 * 64 * 64 * 9) return;
    int k = i / (64 * 64 * 9);
    int r = i % (64 * 64 * 9);
    int oi = r / 9;            // co*64 + ci
    int t = r % 9;
    int co = oi >> 6, ci = oi & 63;
    float cond = fcw[k * 4096 + oi] * 6.0f + fcb[k * 4096 + oi];
    float v = w[i] * (1.0f + cond);
    size_t o = ((size_t)(k * 9 + t) * 64 + co) * 64 + ci;
    unsigned short h = f2bf(v);
    wh[o] = h;
    wl[o] = f2bf(v - bf2f(h));
}

// block-mean pooling, one BLOCK per output element (large s: si<=2)
template<bool DIFF>
__global__ void k_pool_wide(const float* __restrict__ A, const float* __restrict__ Bt,
                            float* __restrict__ out, int pn, int s) {
    int o = blockIdx.x;
    int px = o % pn;
    int t1 = o / pn;
    int py = t1 % pn;
    int t2 = t1 / pn;
    int c = t2 % 64, b = t2 / 64;
    size_t base = (((size_t)(b * 64 + c)) * 32 + (size_t)py * s) * 32 + (size_t)px * s;
    float acc = 0.f;
    int tot = s * s;
    for (int i = threadIdx.x; i < tot; i += blockDim.x) {
        int dy = i / s, dx = i % s;
        float v = A[base + dy * 32 + dx];
        if (DIFF) v -= Bt[base + dy * 32 + dx];
        acc += v;
    }
    acc = blockReduceSum(acc);
    if (threadIdx.x == 0) out[o] = acc / (float)tot;
}

// block-mean pooling, one THREAD per output element (s<=4: si>=3)
template<bool DIFF>
__global__ void k_pool_small(const float* __restrict__ A, const float* __restrict__ Bt,
                             float* __restrict__ out, int pn, int s) {
    int o = blockIdx.x * 256 + threadIdx.x;
    int total = 2048 * pn * pn;
    if (o >= total) return;
    int px = o % pn;
    int t1 = o / pn;
    int py = t1 % pn;
    int t2 = t1 / pn;
    int c = t2 % 64, b = t2 / 64;
    size_t base = (((size_t)(b * 64 + c)) * 32 + (size_t)py * s) * 32 + (size_t)px * s;
    float acc = 0.f;
    for (int dy = 0; dy < s; ++dy)
        for (int dx = 0; dx < s; ++dx) {
            float v = A[base + dy * 32 + dx];
            if (DIFF) v -= Bt[base + dy * 32 + dx];
            acc += v;
        }
    out[o] = acc / (float)(s * s);
}

// NCHW plane-major [64][pn2] per b -> [N][64] f32 + bf16 hi/lo (pn2 multiple of 64)
__global__ void k_trans_nc(const float* __restrict__ src, float* __restrict__ dst,
                           unsigned short* __restrict__ dhi, unsigned short* __restrict__ dlo,
                           int pn2) {
    __shared__ float t[64][65];
    int b = blockIdx.x;
    int p0 = blockIdx.y * 64;
    int lane = threadIdx.x & 63, r4 = threadIdx.x >> 6;
    #pragma unroll
    for (int i = 0; i < 16; ++i) {
        int c = i * 4 + r4;
        t[c][lane] = src[((size_t)b * 64 + c) * pn2 + p0 + lane];
    }
    __syncthreads();
    #pragma unroll
    for (int i = 0; i < 16; ++i) {
        int p = i * 4 + r4;
        size_t o = ((size_t)(b * pn2 + p0 + p)) * 64 + lane;
        float v = t[lane][p];
        unsigned short h = f2bf(v);
        dst[o] = v;
        dhi[o] = h;
        dlo[o] = f2bf(v - bf2f(h));
    }
}

// small transpose for pn<=4
__global__ void k_trans_small(const float* __restrict__ src, float* __restrict__ dst,
                              unsigned short* __restrict__ dhi, unsigned short* __restrict__ dlo,
                              int pn2) {
    int i = blockIdx.x * 256 + threadIdx.x;
    int total = 2048 * pn2;
    if (i >= total) return;
    int c = i & 63, n = i >> 6;
    int b = n / pn2, p = n % pn2;
    float v = src[((size_t)b * 64 + c) * pn2 + p];
    unsigned short h = f2bf(v);
    dst[i] = v;
    dhi[i] = h;
    dlo[i] = f2bf(v - bf2f(h));
}

// ---- MFMA VQ scan: approx scores via split-bf16 (3 terms), per-point top-2 ----
__global__ __launch_bounds__(256) void k_vq_mfma(
        const unsigned short* __restrict__ resthi, const unsigned short* __restrict__ restlo,
        const unsigned short* __restrict__ embhi,  const unsigned short* __restrict__ emblo,
        const float* __restrict__ hesq,
        float* __restrict__ m1v_, int* __restrict__ m1i_,
        float* __restrict__ m2v_, int* __restrict__ m2i_,
        int N, int CPS) {
    __shared__ __align__(16) unsigned short lah[64 * 64];
    __shared__ __align__(16) unsigned short lal[64 * 64];
    __shared__ __align__(16) float lq[64];
    int tid = threadIdx.x;
    int lane = tid & 63, wv = tid >> 6;
    int split = blockIdx.y;
    int p0 = blockIdx.x * 64 + wv * 16;
    int pt = p0 + (lane & 15);
    int ptc = min(pt, N - 1);
    int ko8 = (lane >> 4) * 8;     // channel octet per lane group

    const unsigned short* rb = resthi + (size_t)ptc * 64;
    const unsigned short* rl = restlo + (size_t)ptc * 64;
    s16x8 bh0 = *(const s16x8*)(rb + ko8);
    s16x8 bh1 = *(const s16x8*)(rb + 32 + ko8);
    s16x8 bl0 = *(const s16x8*)(rl + ko8);
    s16x8 bl1 = *(const s16x8*)(rl + 32 + ko8);

    float m1v = FLT_MAX, m2v = FLT_MAX;
    int m1i = 0, m2i = 0;

    int cbeg = split * CPS;
    for (int oc = 0; oc < CPS; oc += 64) {
        int cb = cbeg + oc;
        __syncthreads();
        for (int t = tid; t < 512; t += 256) {
            int cc = t >> 3, part = t & 7;
            int bo = (cc * 128 + part * 16) ^ ((cc & 7) << 4);
            *(uint4*)((char*)lah + bo) = *(const uint4*)(embhi + (size_t)(cb + cc) * 64 + part * 8);
            *(uint4*)((char*)lal + bo) = *(const uint4*)(emblo + (size_t)(cb + cc) * 64 + part * 8);
        }
        if (tid < 64) lq[tid] = hesq[cb + tid];
        __syncthreads();
        #pragma unroll
        for (int sub = 0; sub < 4; ++sub) {
            int cl = sub * 16 + (lane & 15);
            int sw = (cl & 7) << 4;
            int rowb = cl * 128;
            s16x8 ah0 = *(const s16x8*)((const char*)lah + ((rowb + ko8 * 2) ^ sw));
            s16x8 ah1 = *(const s16x8*)((const char*)lah + ((rowb + 64 + ko8 * 2) ^ sw));
            s16x8 al0 = *(const s16x8*)((const char*)lal + ((rowb + ko8 * 2) ^ sw));
            s16x8 al1 = *(const s16x8*)((const char*)lal + ((rowb + 64 + ko8 * 2) ^ sw));
            f32x4 acc = {0.f, 0.f, 0.f, 0.f};
            acc = __builtin_amdgcn_mfma_f32_16x16x32_bf16(ah0, bh0, acc, 0, 0, 0);
            acc = __builtin_amdgcn_mfma_f32_16x16x32_bf16(ah1, bh1, acc, 0, 0, 0);
            acc = __builtin_amdgcn_mfma_f32_16x16x32_bf16(ah0, bl0, acc, 0, 0, 0);
            acc = __builtin_amdgcn_mfma_f32_16x16x32_bf16(ah1, bl1, acc, 0, 0, 0);
            acc = __builtin_amdgcn_mfma_f32_16x16x32_bf16(al0, bh0, acc, 0, 0, 0);
            acc = __builtin_amdgcn_mfma_f32_16x16x32_bf16(al1, bh1, acc, 0, 0, 0);
            int crow = cb + sub * 16 + (lane >> 4) * 4;
            f32x4 q = *(const f32x4*)(lq + sub * 16 + (lane >> 4) * 4);
            #pragma unroll
            for (int r = 0; r < 4; ++r) {
                float s = q[r] - acc[r];
                int c = crow + r;
                bool lt1 = s < m1v, lt2 = s < m2v;
                float nm2v = lt2 ? s : m2v; int nm2i = lt2 ? c : m2i;
                nm2v = lt1 ? m1v : nm2v;    nm2i = lt1 ? m1i : nm2i;
                m1v = lt1 ? s : m1v;        m1i = lt1 ? c : m1i;
                m2v = nm2v; m2i = nm2i;
            }
        }
    }
    #pragma unroll
    for (int off = 16; off <= 32; off <<= 1) {
        float o1v = __shfl_xor(m1v, off, 64); int o1i = __shfl_xor(m1i, off, 64);
        float o2v = __shfl_xor(m2v, off, 64); int o2i = __shfl_xor(m2i, off, 64);
        if (o1v < m1v) {
            float c2v = (m1v < o2v) ? m1v : o2v; int c2i = (m1v < o2v) ? m1i : o2i;
            m1v = o1v; m1i = o1i; m2v = c2v; m2i = c2i;
        } else if (o1v < m2v) {
            m2v = o1v; m2i = o1i;
        }
    }
    if ((lane >> 4) == 0 && pt < N) {
        size_t o = (size_t)split * N + pt;
        m1v_[o] = m1v; m1i_[o] = m1i; m2v_[o] = m2v; m2i_[o] = m2i;
    }
}

// merge split partials; decide or flag for exact fallback
__global__ void k_vq_combine(const float* __restrict__ m1v_, const int* __restrict__ m1i_,
                             const float* __restrict__ m2v_, const int* __restrict__ m2i_,
                             int* __restrict__ idx, int* __restrict__ flag, int* __restrict__ count,
                             int N, int SPLITS) {
    int n = blockIdx.x * 256 + threadIdx.x;
    if (n >= N) return;
    float a1v = m1v_[n], a2v = m2v_[n];
    int a1i = m1i_[n], a2i = m2i_[n];
    for (int s = 1; s < SPLITS; ++s) {
        size_t o = (size_t)s * N + n;
        float b1v = m1v_[o], b2v = m2v_[o];
        int b1i = m1i_[o], b2i = m2i_[o];
        if (b1v < a1v) {
            float c2v = (a1v < b2v) ? a1v : b2v; int c2i = (a1v < b2v) ? a1i : b2i;
            a1v = b1v; a1i = b1i; a2v = c2v; a2i = c2i;
        } else if (b1v < a2v) {
            a2v = b1v; a2i = b1i;
        }
    }
    idx[n] = a1i;
    if (a2v - a1v < TAU) {
        int p = atomicAdd(count, 1);
        flag[p] = n;
    }
}

// exact f32 rescan for flagged points
__global__ __launch_bounds__(256) void k_vq_exact(
        const float* __restrict__ restnc, const float* __restrict__ embed,
        const float* __restrict__ hesq, const int* __restrict__ flag,
        const int* __restrict__ count, unsigned long long* __restrict__ pmin) {
    __shared__ float rs[32 * 64];
    __shared__ unsigned long long red[4];
    int tid = threadIdx.x;
    int lane = tid & 63, wv = tid >> 6;
    int cnt = *count;
    int nb = (cnt + 31) >> 5;
    int ntask = nb * 16;
    for (int task = blockIdx.x; task < ntask; task += gridDim.x) {
        int batch = task >> 4, spl = task & 15;
        int lbase = batch << 5;
        int npts = min(32, cnt - lbase);
        __syncthreads();
        for (int i = tid; i < npts * 64; i += 256) {
            int li = i >> 6;
            rs[i] = restnc[(size_t)flag[lbase + li] * 64 + (i & 63)];
        }
        __syncthreads();
        int code = spl * 256 + tid;
        const float4* e4 = (const float4*)(embed + (size_t)code * 64);
        float4 e[16];
        #pragma unroll
        for (int i = 0; i < 16; ++i) e[i] = e4[i];
        float hq = hesq[code];
        for (int p = 0; p < npts; ++p) {
            const float4* r4 = (const float4*)(rs + p * 64);
            float d0 = 0.f, d1 = 0.f, d2 = 0.f, d3 = 0.f;
            #pragma unroll
            for (int i = 0; i < 16; i += 4) {
                float4 e0 = e[i], e1 = e[i + 1], e2 = e[i + 2], e3 = e[i + 3];
                d0 += e0.x * r4[i].x     + e0.y * r4[i].y     + e0.z * r4[i].z     + e0.w * r4[i].w;
                d1 += e1.x * r4[i + 1].x + e1.y * r4[i + 1].y + e1.z * r4[i + 1].z + e1.w * r4[i + 1].w;
                d2 += e2.x * r4[i + 2].x + e2.y * r4[i + 2].y + e2.z * r4[i + 2].z + e2.w * r4[i + 2].w;
                d3 += e3.x * r4[i + 3].x + e3.y * r4[i + 3].y + e3.z * r4[i + 3].z + e3.w * r4[i + 3].w;
            }
            float s = hq - ((d0 + d1) + (d2 + d3));
            unsigned u = __float_as_uint(s);
            u = (u & 0x80000000u) ? ~u : (u | 0x80000000u);
            unsigned long long pk = (((unsigned long long)u) << 32) | (unsigned)code;
            #pragma unroll
            for (int off = 32; off; off >>= 1) {
                unsigned long long o = __shfl_down(pk, off, 64);
                if (o < pk) pk = o;
            }
            if (lane == 0) red[wv] = pk;
            __syncthreads();
            if (tid == 0) {
                unsigned long long m = red[0];
                for (int w = 1; w < 4; ++w) if (red[w] < m) m = red[w];
                atomicMin(pmin + flag[lbase + p], m);
            }
            __syncthreads();
        }
    }
}

// gather codebook rows (pmin overrides idx for flagged points) -> hs [N][64] NHWC
__global__ void k_gather(const int* __restrict__ idx, const unsigned long long* __restrict__ pmin,
                         const float* __restrict__ embed, float* __restrict__ hs, int N) {
    int i = blockIdx.x * 256 + threadIdx.x;
    if (i >= N * 64) return;
    int n = i >> 6, c = i & 63;
    unsigned long long pv = pmin[n];
    int id = (pv != 0xFFFFFFFFFFFFFFFFull) ? (int)(pv & 0xFFFFFFFFull) : idx[n];
    hs[i] = embed[(size_t)id * 64 + c];
}

// bilinear upsample pn->32: NHWC small -> NHWC full (f32 + bf16 hi/lo)
__global__ void k_upsample(const float* __restrict__ hs, float* __restrict__ hupf,
                           unsigned short* __restrict__ huph, unsigned short* __restrict__ hupl,
                           int pn) {
    int i = blockIdx.x * 256 + threadIdx.x;
    if (i >= N_ELEM) return;
    int c = i & 63, x = (i >> 6) & 31, y = (i >> 11) & 31, b = i >> 16;
    float scale = (float)pn * (1.0f / 32.0f);
    float sy = (y + 0.5f) * scale - 0.5f;
    float sx = (x + 0.5f) * scale - 0.5f;
    float fy0 = floorf(sy), fx0 = floorf(sx);
    float wy = sy - fy0, wx = sx - fx0;
    int y0 = max(0, min(pn - 1, (int)fy0));
    int y1 = max(0, min(pn - 1, (int)fy0 + 1));
    int x0 = max(0, min(pn - 1, (int)fx0));
    int x1 = max(0, min(pn - 1, (int)fx0 + 1));
    const float* hb = hs + (size_t)b * pn * pn * 64 + c;
    float v00 = hb[(size_t)(y0 * pn + x0) * 64];
    float v01 = hb[(size_t)(y0 * pn + x1) * 64];
    float v10 = hb[(size_t)(y1 * pn + x0) * 64];
    float v11 = hb[(size_t)(y1 * pn + x1) * 64];
    float v = (1.f - wy) * ((1.f - wx) * v00 + wx * v01) + wy * ((1.f - wx) * v10 + wx * v11);
    hupf[i] = v;
    unsigned short h = f2bf(v);
    huph[i] = h;
    hupl[i] = f2bf(v - bf2f(h));
}

// si=5: hs is already NHWC full-res; just emit bf16 hi/lo
__global__ void k_hilo(const float* __restrict__ hs,
                       unsigned short* __restrict__ huph, unsigned short* __restrict__ hupl) {
    int i = blockIdx.x * 256 + threadIdx.x;
    if (i >= N_ELEM) return;
    float v = hs[i];
    unsigned short h = f2bf(v);
    huph[i] = h;
    hupl[i] = f2bf(v - bf2f(h));
}

// ---- MFMA 3x3 conv as 9 shifted GEMMs + blend + state update + vq partial ----
// grid (32 b, 8 row-groups); block 256 = 4 waves; wave w -> co group w*16.
// X halo (6 rows x 34 cols x 64 ci) staged in LDS pixel-major bf16 hi/lo, XOR-swizzled.
// 4-term split (WhXh+WhXl+WlXh+WlXl) => f32-quality numerics.
__global__ __launch_bounds__(256) void k_conv_mfma(
        const unsigned short* __restrict__ huph, const unsigned short* __restrict__ hupl,
        const float* __restrict__ hupf,
        const unsigned short* __restrict__ wh, const unsigned short* __restrict__ wl,
        const float* __restrict__ bias, const float* __restrict__ f_in,
        float* __restrict__ f_hat, float* __restrict__ f_rest,
        float* __restrict__ vq_part) {
    __shared__ __align__(16) unsigned short Xh[6 * 34 * 64];
    __shared__ __align__(16) unsigned short Xl[6 * 34 * 64];
    int b = blockIdx.x, rg = blockIdx.y;
    int y0 = rg * 4;
    int tid = threadIdx.x;
    int lane = tid & 63, wv = tid >> 6;
    int co0 = wv * 16;
    int cr = lane & 15, oct = lane >> 4;

    // stage halo: rows y0-1..y0+4, cols -1..32, zero-padded
    for (int q = tid; q < 6 * 34 * 8; q += 256) {
        int pl = q >> 3, o8 = q & 7;
        int lr = pl / 34, lc = pl % 34;
        int gy = y0 + lr - 1, gx = lc - 1;
        int bo = (pl * 128 + o8 * 16) ^ ((lc & 7) << 4);
        uint4 vh = {0, 0, 0, 0}, vl = {0, 0, 0, 0};
        if (gy >= 0 && gy < 32 && gx >= 0 && gx < 32) {
            size_t g = (((size_t)(b * 32 + gy)) * 32 + gx) * 64 + o8 * 8;
            vh = *(const uint4*)(huph + g);
            vl = *(const uint4*)(hupl + g);
        }
        *(uint4*)((char*)Xh + bo) = vh;
        *(uint4*)((char*)Xl + bo) = vl;
    }
    __syncthreads();

    f32x4 acc[8];
    #pragma unroll
    for (int ps = 0; ps < 8; ++ps) acc[ps] = (f32x4){0.f, 0.f, 0.f, 0.f};

    for (int t = 0; t < 9; ++t) {
        int dy = t / 3, dx = t % 3;
        #pragma unroll
        for (int cc = 0; cc < 2; ++cc) {
            size_t wo = ((size_t)t * 64 + co0 + cr) * 64 + cc * 32 + oct * 8;
            s16x8 Ah = *(const s16x8*)(wh + wo);
            s16x8 Al = *(const s16x8*)(wl + wo);
            #pragma unroll
            for (int ps = 0; ps < 8; ++ps) {
                int px = ps * 16 + cr;
                int lr = (px >> 5) + dy;
                int lc = (px & 31) + dx;
                int bo = ((lr * 34 + lc) * 128 + cc * 64 + oct * 16) ^ ((lc & 7) << 4);
                s16x8 Bh = *(const s16x8*)((const char*)Xh + bo);
                s16x8 Bl = *(const s16x8*)((const char*)Xl + bo);
                acc[ps] = __builtin_amdgcn_mfma_f32_16x16x32_bf16(Ah, Bh, acc[ps], 0, 0, 0);
                acc[ps] = __builtin_amdgcn_mfma_f32_16x16x32_bf16(Ah, Bl, acc[ps], 0, 0, 0);
                acc[ps] = __builtin_amdgcn_mfma_f32_16x16x32_bf16(Al, Bh, acc[ps], 0, 0, 0);
                acc[ps] = __builtin_amdgcn_mfma_f32_16x16x32_bf16(Al, Bl, acc[ps], 0, 0, 0);
            }
        }
    }

    // epilogue: D row (co) = oct*4 + r, D col (px) = cr
    const float* hupb = hupf + (size_t)b * 65536;
    float local = 0.f;
    #pragma unroll
    for (int ps = 0; ps < 8; ++ps) {
        int px = ps * 16 + cr;
        int y = y0 + (px >> 5), x = px & 31;
        #pragma unroll
        for (int r = 0; r < 4; ++r) {
            int co = co0 + oct * 4 + r;
            float hv = hupb[(size_t)(y * 32 + x) * 64 + co];
            float hconv = acc[ps][r] + bias[co];
            float hout = 0.5f * hv + 0.5f * hconv;
            size_t o = (((size_t)(b * 64 + co)) * 32 + y) * 32 + x;
            float fh = f_hat[o] + hout;
            f_hat[o] = fh;
            f_rest[o] -= hout;
            float d = fh - f_in[o];
            local += d * d;
        }
    }
    local = blockReduceSum(local);
    if (tid == 0) vq_part[b * 8 + rg] = local;
}

// sum of squares -> per-block partials
__global__ void k_sqsum(const float* __restrict__ v, float* __restrict__ part, int M) {
    float local = 0.f;
    for (int i = blockIdx.x * 256 + threadIdx.x; i < M; i += gridDim.x * 256) {
        float a = v[i];
        local += a * a;
    }
    local = blockReduceSum(local);
    if (threadIdx.x == 0) part[blockIdx.x] = local;
}

// final: reduce vq partials (6x256) and commit partials (6x512)
__global__ void k_final(const float* __restrict__ vqp, const float* __restrict__ cmp,
                        float* __restrict__ out) {
    const int pn2s[6] = {1, 4, 16, 64, 256, 1024};
    float commit = 0.f;
    for (int si = 0; si < 6; ++si) {
        float l = (threadIdx.x < 256) ? vqp[si * 256 + threadIdx.x] : 0.f;
        l = blockReduceSum(l);
        if (threadIdx.x == 0) out[N_ELEM + si] = l / (float)N_ELEM;

        float csum = 0.f;
        for (int i = threadIdx.x; i < 512; i += 256) csum += cmp[si * 512 + i];
        csum = blockReduceSum(csum);
        if (threadIdx.x == 0) commit += csum / (float)(2048 * pn2s[si]) * 0.25f;
    }
    if (threadIdx.x == 0) out[N_ELEM + 6] = commit / 6.0f;
}

extern "C" void kernel_launch(void* const* d_in, const int* in_sizes, int n_in,
                              void* d_out, int out_size, void* d_ws, size_t ws_size,
                              hipStream_t stream) {
    const float* f     = (const float*)d_in[0];
    const float* embed = (const float*)d_in[1];
    const float* convw = (const float*)d_in[2];
    const float* convb = (const float*)d_in[3];
    const float* fcw   = (const float*)d_in[4];
    const float* fcb   = (const float*)d_in[5];
    float* out = (float*)d_out;
    float* ws  = (float*)d_ws;

    float* f_rest  = ws;                                        // 2097152
    float* poolhup = ws + 2097152;                              // 2097152 (pooled & hupf alias)
    float* restnc  = ws + 4194304;                              // 2097152 (hs alias after exact)
    float* hs      = restnc;
    unsigned short* resthi = (unsigned short*)(ws + 6291456);   // 2097152 u16 (alias huph)
    unsigned short* restlo = (unsigned short*)(ws + 7340032);   // 2097152 u16 (alias hupl)
    unsigned short* huph   = resthi;
    unsigned short* hupl   = restlo;
    unsigned short* embhi  = (unsigned short*)(ws + 8388608);   // 262144 u16
    unsigned short* emblo  = (unsigned short*)(ws + 8519680);   // 262144 u16
    unsigned short* wmodh  = (unsigned short*)(ws + 8650752);   // 147456 u16
    unsigned short* wmodl  = (unsigned short*)(ws + 8724480);   // 147456 u16
    float* hesq   = ws + 8798208;                               // 4096
    float* m1v    = ws + 8802304;                               // 65536
    float* m2v    = ws + 8867840;                               // 65536
    int*   m1i    = (int*)(ws + 8933376);                       // 65536
    int*   m2i    = (int*)(ws + 8998912);                       // 65536
    int*   idx    = (int*)(ws + 9064448);                       // 32768
    int*   flag   = (int*)(ws + 9097216);                       // 32768
    int*   count  = (int*)(ws + 9129984);                       // 64 (pad)
    unsigned long long* pmin = (unsigned long long*)(ws + 9130048); // 32768 u64
    float* vqp    = ws + 9195584;                               // 1536 (6*256)
    float* cmp    = ws + 9197120;                               // 3072 (6*512)

    hipMemsetAsync(d_out, 0, (size_t)out_size * sizeof(float), stream);
    hipMemcpyAsync(f_rest, f, (size_t)N_ELEM * sizeof(float), hipMemcpyDeviceToDevice, stream);
    k_wmod<<<(147456 + 255) / 256, 256, 0, stream>>>(convw, fcw, fcb, wmodh, wmodl);
    k_embprep<<<16, 256, 0, stream>>>(embed, hesq, embhi, emblo);

    const int pns[6]    = {1, 2, 4, 8, 16, 32};
    const int splits[6] = {64, 32, 16, 8, 4, 2};
    const int kidx[6]   = {0, 0, 1, 2, 3, 3};

    for (int si = 0; si < 6; ++si) {
        int pn = pns[si], s = 32 / pn, pn2 = pn * pn;
        int N = 32 * pn2, SPL = splits[si], CPS = 4096 / SPL;
        float* pooled = poolhup;
        float* hupf = poolhup;

        // 1. downsample f_rest -> rest [N][64] f32 + bf16 hi/lo
        if (si <= 2) {
            k_pool_wide<false><<<2048 * pn2, (s >= 16 ? 256 : 64), 0, stream>>>(f_rest, nullptr, pooled, pn, s);
            k_trans_small<<<(N * 64 + 255) / 256, 256, 0, stream>>>(pooled, restnc, resthi, restlo, pn2);
        } else if (si <= 4) {
            k_pool_small<false><<<(2048 * pn2 + 255) / 256, 256, 0, stream>>>(f_rest, nullptr, pooled, pn, s);
            k_trans_nc<<<dim3(32, pn2 / 64), 256, 0, stream>>>(pooled, restnc, resthi, restlo, pn2);
        } else {
            k_trans_nc<<<dim3(32, 16), 256, 0, stream>>>(f_rest, restnc, resthi, restlo, 1024);
        }

        // 2. nearest codebook entry: MFMA approx top-2 -> combine -> exact fallback
        hipMemsetAsync(count, 0, sizeof(int), stream);
        hipMemsetAsync(pmin, 0xFF, (size_t)N * 8, stream);
        k_vq_mfma<<<dim3((N + 63) / 64, SPL), 256, 0, stream>>>(resthi, restlo, embhi, emblo, hesq,
                                                                m1v, m1i, m2v, m2i, N, CPS);
        k_vq_combine<<<(N + 255) / 256, 256, 0, stream>>>(m1v, m1i, m2v, m2i, idx, flag, count, N, SPL);
        k_vq_exact<<<1024, 256, 0, stream>>>(restnc, embed, hesq, flag, count, pmin);

        // 3. gather + upsample to full-res NHWC (f32 + bf16 hi/lo)
        k_gather<<<(N * 64 + 255) / 256, 256, 0, stream>>>(idx, pmin, embed, hs, N);
        if (si < 5) {
            k_upsample<<<(N_ELEM + 255) / 256, 256, 0, stream>>>(hs, hupf, huph, hupl, pn);
        } else {
            k_hilo<<<(N_ELEM + 255) / 256, 256, 0, stream>>>(hs, huph, hupl);
            hupf = hs;   // hs is already NHWC full-res f32
        }

        // 4. MFMA Phi conv + blend + state update + vq loss partials
        k_conv_mfma<<<dim3(32, 8), 256, 0, stream>>>(huph, hupl, hupf,
                                                     wmodh + kidx[si] * 36864, wmodl + kidx[si] * 36864,
                                                     convb + kidx[si] * 64, f, out, f_rest,
                                                     vqp + si * 256);

        // 5. commit term
        if (si <= 2) k_pool_wide<true><<<2048 * pn2, (s >= 16 ? 256 : 64), 0, stream>>>(out, f, pooled, pn, s);
        else         k_pool_small<true><<<(2048 * pn2 + 255) / 256, 256, 0, stream>>>(out, f, pooled, pn, s);
        k_sqsum<<<512, 256, 0, stream>>>(pooled, cmp + si * 512, 2048 * pn2);
    }

    k_final<<<1, 256, 0, stream>>>(vqp, cmp, out);
}